// Round 1
// baseline (2530.647 us; speedup 1.0000x reference)
//
#include <hip/hip_runtime.h>

#define B_  4
#define S_  2048
#define D_  768
#define NH_ 4
#define DH_ 192

typedef short  s8v __attribute__((ext_vector_type(8)));
typedef float  f4v __attribute__((ext_vector_type(4)));
typedef unsigned short ushort_t;

static __device__ __forceinline__ ushort_t f2bf(float f) {
    union { float f; unsigned u; } v; v.f = f;
    unsigned r = v.u + 0x7fffu + ((v.u >> 16) & 1u);
    return (ushort_t)(r >> 16);
}
static __device__ __forceinline__ float bf2f(ushort_t b) {
    union { unsigned u; float f; } v; v.u = ((unsigned)b) << 16;
    return v.f;
}
static __device__ __forceinline__ f4v mfma16(s8v a, s8v b, f4v c) {
    return __builtin_amdgcn_mfma_f32_16x16x32_bf16(a, b, c, 0, 0, 0);
}

// ---------------------------------------------------------------------------
// Kernel 1: causal depthwise conv1d + swish -> x_conv (bf16); also x -> bf16.
// ---------------------------------------------------------------------------
__global__ void conv_kernel(const float* __restrict__ x, const float* __restrict__ ck,
                            const float* __restrict__ cb,
                            ushort_t* __restrict__ xconv, ushort_t* __restrict__ xb) {
    int idx = blockIdx.x * blockDim.x + threadIdx.x;   // over B*S*D/4
    const int nd4 = D_ / 4;
    int d4 = idx % nd4;
    int bs = idx / nd4;
    int s = bs % S_;
    int b = bs / S_;
    int d = d4 * 4;

    float4 acc = *(const float4*)(cb + d);
    float4 xcur = make_float4(0.f, 0.f, 0.f, 0.f);
#pragma unroll
    for (int k = 0; k < 4; ++k) {
        int sk = s - 3 + k;
        float4 xv = make_float4(0.f, 0.f, 0.f, 0.f);
        if (sk >= 0) xv = *(const float4*)(x + ((size_t)(b * S_ + sk) * D_ + d));
        if (k == 3) xcur = xv;
        float4 kv = *(const float4*)(ck + (size_t)k * D_ + d);
        acc.x += xv.x * kv.x; acc.y += xv.y * kv.y;
        acc.z += xv.z * kv.z; acc.w += xv.w * kv.w;
    }
    // swish
    float c0 = acc.x / (1.f + __expf(-acc.x));
    float c1 = acc.y / (1.f + __expf(-acc.y));
    float c2 = acc.z / (1.f + __expf(-acc.z));
    float c3 = acc.w / (1.f + __expf(-acc.w));

    size_t base = (size_t)bs * D_ + d;
    ushort4 pc; pc.x = f2bf(c0); pc.y = f2bf(c1); pc.z = f2bf(c2); pc.w = f2bf(c3);
    *(ushort4*)(xconv + base) = pc;
    ushort4 px; px.x = f2bf(xcur.x); px.y = f2bf(xcur.y); px.z = f2bf(xcur.z); px.w = f2bf(xcur.w);
    *(ushort4*)(xb + base) = px;
}

// ---------------------------------------------------------------------------
// Kernel 2: gate pre-activation GEMMs.
// G layout: [s][h][g][b][e] bf16 (g in {i,f,z,o}), cell_bias folded in.
// grid: (32 s-blocks, NH, 2) ; p=0 -> {i,f} from x_conv ; p=1 -> {z,o} from x.
// 768 threads = 12 waves; wave w owns e-tile w for both gates of its pair.
// ---------------------------------------------------------------------------
__launch_bounds__(768)
__global__ void gates_kernel(const ushort_t* __restrict__ xconv, const ushort_t* __restrict__ xb,
                             const float* __restrict__ Wi, const float* __restrict__ Wf,
                             const float* __restrict__ Wz, const float* __restrict__ Wo,
                             const float* __restrict__ cbias, ushort_t* __restrict__ G) {
    int sb = blockIdx.x, h = blockIdx.y, p = blockIdx.z;
    const ushort_t* X = (p == 0) ? xconv : xb;
    const float* W0 = (p == 0) ? Wi : Wz;
    const float* W1 = (p == 0) ? Wf : Wo;
    int g0 = 2 * p, g1 = 2 * p + 1;

    int tid = threadIdx.x;
    int lane = tid & 63;
    int w = tid >> 6;                 // 0..11 = e-tile

    int col = w * 16 + (lane & 15);   // e
    int kq0 = (lane >> 4) * 8;

    // B fragments (weights), bf16, in registers
    s8v B0[6], B1[6];
#pragma unroll
    for (int kt = 0; kt < 6; ++kt) {
        const float* w0p = W0 + ((size_t)(h * DH_ + kt * 32 + kq0)) * DH_ + col;
        const float* w1p = W1 + ((size_t)(h * DH_ + kt * 32 + kq0)) * DH_ + col;
        s8v f0, f1;
#pragma unroll
        for (int j = 0; j < 8; ++j) {
            f0[j] = (short)f2bf(w0p[(size_t)j * DH_]);
            f1[j] = (short)f2bf(w1p[(size_t)j * DH_]);
        }
        B0[kt] = f0; B1[kt] = f1;
    }
    float bias0 = cbias[(size_t)g0 * D_ + h * DH_ + col];
    float bias1 = cbias[(size_t)g1 * D_ + h * DH_ + col];

    int b_l = lane & 3;
    int ds_l = (lane >> 2) & 3;

    for (int mt = 0; mt < 16; ++mt) {
        int s = sb * 64 + mt * 4 + ds_l;
        const ushort_t* ap = X + ((size_t)(b_l * S_ + s) * D_ + h * DH_ + kq0);
        s8v A[6];
#pragma unroll
        for (int kt = 0; kt < 6; ++kt) A[kt] = *(const s8v*)(ap + kt * 32);
        f4v a0 = {0.f, 0.f, 0.f, 0.f}, a1 = {0.f, 0.f, 0.f, 0.f};
#pragma unroll
        for (int kt = 0; kt < 6; ++kt) {
            a0 = mfma16(A[kt], B0[kt], a0);
            a1 = mfma16(A[kt], B1[kt], a1);
        }
        // epilogue: reg r -> b=r ; quad -> s offset
        int sro = sb * 64 + mt * 4 + (lane >> 4);
        size_t base0 = ((size_t)(sro * NH_ + h) * 4 + g0) * (4 * DH_);
        size_t base1 = ((size_t)(sro * NH_ + h) * 4 + g1) * (4 * DH_);
#pragma unroll
        for (int r = 0; r < 4; ++r) {
            G[base0 + r * DH_ + col] = f2bf(a0[r] + bias0);
            G[base1 + r * DH_ + col] = f2bf(a1[r] + bias1);
        }
    }
}

// ---------------------------------------------------------------------------
// Kernel 3: the sequential recurrence. One workgroup per head (4 WGs).
// 768 threads = 12 waves; wave w owns e-tile w across all 4 gates.
// Batch (4) packed into MFMA M rows. R weights live in registers as bf16.
// ys layout: [s][h][b][e] bf16.
// ---------------------------------------------------------------------------
__launch_bounds__(768)
__global__ void recur_kernel(const ushort_t* __restrict__ G, const float* __restrict__ Rw,
                             ushort_t* __restrict__ ys) {
    const int h = blockIdx.x;
    const int tid = threadIdx.x;
    const int lane = tid & 63;
    const int w = tid >> 6;

    __shared__ ushort_t h_lds[4 * 208];      // [b][e], padded stride 208
    __shared__ f4v rec_lds[768];             // [t = b*192+e] -> (i,f,z,o)

    // preload R fragments: B[k=(lane>>4)*8+j][e = w*16 + (lane&15)]
    s8v Bf[4][6];
    {
        int col = w * 16 + (lane & 15);
        int kq0 = (lane >> 4) * 8;
#pragma unroll
        for (int g = 0; g < 4; ++g)
#pragma unroll
            for (int kt = 0; kt < 6; ++kt) {
                const float* rp = Rw + ((size_t)((g * NH_ + h) * DH_ + kt * 32 + kq0)) * DH_ + col;
                s8v f;
#pragma unroll
                for (int j = 0; j < 8; ++j) f[j] = (short)f2bf(rp[(size_t)j * DH_]);
                Bf[g][kt] = f;
            }
    }

    for (int i = tid; i < 4 * 208; i += 768) h_lds[i] = 0;

    float m_st = 0.f, c_st = 0.f, n_st = 0.f;
    const int b_idx = tid / DH_;
    const int e_idx = tid % DH_;
    const int arow = lane & 3;
    const int kq = (lane >> 4) * 8;

    // G prefetch (distance 1)
    ushort_t gi_n, gf_n, gz_n, go_n;
    {
        const ushort_t* gp = G + ((size_t)(0 * NH_ + h) * 4) * (4 * DH_) + tid;
        gi_n = gp[0]; gf_n = gp[768]; gz_n = gp[2 * 768]; go_n = gp[3 * 768];
    }

    __syncthreads();

    for (int s = 0; s < S_; ++s) {
        ushort_t gi = gi_n, gf = gf_n, gz = gz_n, go = go_n;
        {   // prefetch next step's gate inputs
            int sn = (s + 1 < S_) ? (s + 1) : s;
            const ushort_t* gp = G + ((size_t)(sn * NH_ + h) * 4) * (4 * DH_) + tid;
            gi_n = gp[0]; gf_n = gp[768]; gz_n = gp[2 * 768]; go_n = gp[3 * 768];
        }

        // A fragments (h state) from LDS
        s8v A[6];
#pragma unroll
        for (int kt = 0; kt < 6; ++kt)
            A[kt] = *(const s8v*)&h_lds[arow * 208 + kt * 32 + kq];

        f4v acc[4];
#pragma unroll
        for (int g = 0; g < 4; ++g) { acc[g][0] = 0.f; acc[g][1] = 0.f; acc[g][2] = 0.f; acc[g][3] = 0.f; }
#pragma unroll
        for (int g = 0; g < 4; ++g)
#pragma unroll
            for (int kt = 0; kt < 6; ++kt)
                acc[g] = mfma16(A[kt], Bf[g][kt], acc[g]);

        // rec -> LDS: valid lanes 0-15, regs = batches
        if (lane < 16) {
            int e = w * 16 + lane;
#pragma unroll
            for (int bb = 0; bb < 4; ++bb) {
                f4v v;
                v[0] = acc[0][bb]; v[1] = acc[1][bb]; v[2] = acc[2][bb]; v[3] = acc[3][bb];
                rec_lds[bb * DH_ + e] = v;
            }
        }
        __syncthreads();

        // gating (elementwise per (b,e) = tid)
        f4v r = rec_lds[tid];
        float it = r[0] + bf2f(gi);
        float ft = r[1] + bf2f(gf);
        float zt = r[2] + bf2f(gz);
        float ot = r[3] + bf2f(go);

        float mn = fmaxf(ft + m_st, it);
        float ia = __expf(it - mn);
        float fa = __expf(ft + m_st - mn);
        float ez = __expf(2.f * zt);
        float th = 1.f - 2.f / (ez + 1.f);
        float cn = fa * c_st + ia * th;
        float nn = fa * n_st + ia;
        float sg = 1.f / (1.f + __expf(-ot));
        float hn = sg * cn / nn;
        m_st = mn; c_st = cn; n_st = nn;

        ushort_t hb = f2bf(hn);
        __syncthreads();              // all rec/A reads done before h_lds overwrite
        h_lds[b_idx * 208 + e_idx] = hb;
        ys[(size_t)(s * NH_ + h) * (4 * DH_) + tid] = hb;
        __syncthreads();
    }
}

// ---------------------------------------------------------------------------
// Kernel 4: multi-head layernorm. One wave per (b,s,h) group of 192.
// ---------------------------------------------------------------------------
__global__ void ln_kernel(const ushort_t* __restrict__ ys, const float* __restrict__ gn,
                          float* __restrict__ out) {
    int gw = (blockIdx.x * blockDim.x + threadIdx.x) >> 6;   // 0 .. 32767
    int lane = threadIdx.x & 63;
    int b = gw & 3;
    int h = (gw >> 2) & 3;
    int s = gw >> 4;

    const ushort_t* yp = ys + (size_t)gw * DH_;
    float v0 = bf2f(yp[lane]);
    float v1 = bf2f(yp[lane + 64]);
    float v2 = bf2f(yp[lane + 128]);
    float sum = v0 + v1 + v2;
    float sq  = v0 * v0 + v1 * v1 + v2 * v2;
#pragma unroll
    for (int off = 32; off > 0; off >>= 1) {
        sum += __shfl_xor(sum, off, 64);
        sq  += __shfl_xor(sq,  off, 64);
    }
    float mu  = sum * (1.f / 192.f);
    float var = sq * (1.f / 192.f) - mu * mu;
    float rs  = rsqrtf(var + 1e-5f);

    float* op = out + (size_t)(b * S_ + s) * D_ + h * DH_;
    const float* gp = gn + h * DH_;
    op[lane]       = (v0 - mu) * rs * gp[lane];
    op[lane + 64]  = (v1 - mu) * rs * gp[lane + 64];
    op[lane + 128] = (v2 - mu) * rs * gp[lane + 128];
}

// ---------------------------------------------------------------------------
extern "C" void kernel_launch(void* const* d_in, const int* in_sizes, int n_in,
                              void* d_out, int out_size, void* d_ws, size_t ws_size,
                              hipStream_t stream) {
    const float* x     = (const float*)d_in[0];
    const float* ck    = (const float*)d_in[1];
    const float* cb    = (const float*)d_in[2];
    const float* Wi    = (const float*)d_in[3];
    const float* Wf    = (const float*)d_in[4];
    const float* Wz    = (const float*)d_in[5];
    const float* Wo    = (const float*)d_in[6];
    const float* Rw    = (const float*)d_in[7];
    const float* cbias = (const float*)d_in[8];
    const float* gn    = (const float*)d_in[9];
    float* out = (float*)d_out;

    const size_t nBSD = (size_t)B_ * S_ * D_;              // 6291456
    ushort_t* xconv = (ushort_t*)d_ws;
    ushort_t* xb    = xconv + nBSD;
    ushort_t* G     = xb + nBSD;                           // S*NH*4*B*DH = 25165824
    ushort_t* ys    = G + (size_t)S_ * NH_ * 4 * B_ * DH_; // 6291456

    conv_kernel<<<dim3(B_ * S_ * D_ / 4 / 256), dim3(256), 0, stream>>>(x, ck, cb, xconv, xb);
    gates_kernel<<<dim3(32, NH_, 2), dim3(768), 0, stream>>>(xconv, xb, Wi, Wf, Wz, Wo, cbias, G);
    recur_kernel<<<dim3(NH_), dim3(768), 0, stream>>>(G, Rw, ys);
    ln_kernel<<<dim3(8192), dim3(256), 0, stream>>>(ys, gn, out);
}

// Round 2
// 2077.234 us; speedup vs baseline: 1.2183x; 1.2183x over previous
//
#include <hip/hip_runtime.h>

#define B_  4
#define S_  2048
#define D_  768
#define NH_ 4
#define DH_ 192

typedef short  s8v __attribute__((ext_vector_type(8)));
typedef float  f4v __attribute__((ext_vector_type(4)));
typedef unsigned short ushort_t;

static __device__ __forceinline__ ushort_t f2bf(float f) {
    union { float f; unsigned u; } v; v.f = f;
    unsigned r = v.u + 0x7fffu + ((v.u >> 16) & 1u);
    return (ushort_t)(r >> 16);
}
static __device__ __forceinline__ float bf2f(ushort_t b) {
    union { unsigned u; float f; } v; v.u = ((unsigned)b) << 16;
    return v.f;
}
static __device__ __forceinline__ f4v mfma16(s8v a, s8v b, f4v c) {
    return __builtin_amdgcn_mfma_f32_16x16x32_bf16(a, b, c, 0, 0, 0);
}

// ---------------------------------------------------------------------------
// Kernel 1: causal depthwise conv1d + swish -> x_conv (bf16); also x -> bf16.
// ---------------------------------------------------------------------------
__global__ void conv_kernel(const float* __restrict__ x, const float* __restrict__ ck,
                            const float* __restrict__ cb,
                            ushort_t* __restrict__ xconv, ushort_t* __restrict__ xb) {
    int idx = blockIdx.x * blockDim.x + threadIdx.x;   // over B*S*D/4
    const int nd4 = D_ / 4;
    int d4 = idx % nd4;
    int bs = idx / nd4;
    int s = bs % S_;
    int b = bs / S_;
    int d = d4 * 4;

    float4 acc = *(const float4*)(cb + d);
    float4 xcur = make_float4(0.f, 0.f, 0.f, 0.f);
#pragma unroll
    for (int k = 0; k < 4; ++k) {
        int sk = s - 3 + k;
        float4 xv = make_float4(0.f, 0.f, 0.f, 0.f);
        if (sk >= 0) xv = *(const float4*)(x + ((size_t)(b * S_ + sk) * D_ + d));
        if (k == 3) xcur = xv;
        float4 kv = *(const float4*)(ck + (size_t)k * D_ + d);
        acc.x += xv.x * kv.x; acc.y += xv.y * kv.y;
        acc.z += xv.z * kv.z; acc.w += xv.w * kv.w;
    }
    float c0 = acc.x / (1.f + __expf(-acc.x));
    float c1 = acc.y / (1.f + __expf(-acc.y));
    float c2 = acc.z / (1.f + __expf(-acc.z));
    float c3 = acc.w / (1.f + __expf(-acc.w));

    size_t base = (size_t)bs * D_ + d;
    ushort4 pc; pc.x = f2bf(c0); pc.y = f2bf(c1); pc.z = f2bf(c2); pc.w = f2bf(c3);
    *(ushort4*)(xconv + base) = pc;
    ushort4 px; px.x = f2bf(xcur.x); px.y = f2bf(xcur.y); px.z = f2bf(xcur.z); px.w = f2bf(xcur.w);
    *(ushort4*)(xb + base) = px;
}

// ---------------------------------------------------------------------------
// Kernel 2: gate pre-activation GEMMs.
// G layout: [s][h][b][e][g] bf16 (g in {i,f,z,o}), cell_bias folded in.
// grid: (32 s-blocks, NH, 2) ; p=0 -> {i,f} from x_conv ; p=1 -> {z,o} from x.
// ---------------------------------------------------------------------------
__launch_bounds__(768)
__global__ void gates_kernel(const ushort_t* __restrict__ xconv, const ushort_t* __restrict__ xb,
                             const float* __restrict__ Wi, const float* __restrict__ Wf,
                             const float* __restrict__ Wz, const float* __restrict__ Wo,
                             const float* __restrict__ cbias, ushort_t* __restrict__ G) {
    int sb = blockIdx.x, h = blockIdx.y, p = blockIdx.z;
    const ushort_t* X = (p == 0) ? xconv : xb;
    const float* W0 = (p == 0) ? Wi : Wz;
    const float* W1 = (p == 0) ? Wf : Wo;
    int g0 = 2 * p, g1 = 2 * p + 1;

    int tid = threadIdx.x;
    int lane = tid & 63;
    int w = tid >> 6;                 // 0..11 = e-tile

    int col = w * 16 + (lane & 15);   // e
    int kq0 = (lane >> 4) * 8;

    s8v B0[6], B1[6];
#pragma unroll
    for (int kt = 0; kt < 6; ++kt) {
        const float* w0p = W0 + ((size_t)(h * DH_ + kt * 32 + kq0)) * DH_ + col;
        const float* w1p = W1 + ((size_t)(h * DH_ + kt * 32 + kq0)) * DH_ + col;
        s8v f0, f1;
#pragma unroll
        for (int j = 0; j < 8; ++j) {
            f0[j] = (short)f2bf(w0p[(size_t)j * DH_]);
            f1[j] = (short)f2bf(w1p[(size_t)j * DH_]);
        }
        B0[kt] = f0; B1[kt] = f1;
    }
    float bias0 = cbias[(size_t)g0 * D_ + h * DH_ + col];
    float bias1 = cbias[(size_t)g1 * D_ + h * DH_ + col];

    int b_l = lane & 3;
    int ds_l = (lane >> 2) & 3;

    for (int mt = 0; mt < 16; ++mt) {
        int s = sb * 64 + mt * 4 + ds_l;
        const ushort_t* ap = X + ((size_t)(b_l * S_ + s) * D_ + h * DH_ + kq0);
        s8v A[6];
#pragma unroll
        for (int kt = 0; kt < 6; ++kt) A[kt] = *(const s8v*)(ap + kt * 32);
        f4v a0 = {0.f, 0.f, 0.f, 0.f}, a1 = {0.f, 0.f, 0.f, 0.f};
#pragma unroll
        for (int kt = 0; kt < 6; ++kt) {
            a0 = mfma16(A[kt], B0[kt], a0);
            a1 = mfma16(A[kt], B1[kt], a1);
        }
        // epilogue: C row = (lane>>4)*4 + r ; r = batch, lane>>4 = s offset
        int sro = sb * 64 + mt * 4 + (lane >> 4);
#pragma unroll
        for (int r = 0; r < 4; ++r) {
            size_t idx = (((size_t)(sro * NH_ + h) * B_ + r) * DH_ + col) * 4;
            ushort2 pr;
            pr.x = f2bf(a0[r] + bias0);
            pr.y = f2bf(a1[r] + bias1);
            *(ushort2*)(G + idx + 2 * p) = pr;
        }
    }
}

// ---------------------------------------------------------------------------
// Kernel 3: sequential recurrence. One WG per head. 768 thr = 12 waves.
// Batch b occupies A-rows 4b..4b+3 (content h[row>>2]) so C-row 4b lands in
// lane 16b reg 0 -> every lane holds its own (b,e) pre-acts for all 4 gates.
// 1 barrier per step; double-buffered h state in LDS.
// ys layout: [s][h][b][e] bf16.
// ---------------------------------------------------------------------------
__launch_bounds__(768)
__global__ void recur_kernel(const ushort_t* __restrict__ G, const float* __restrict__ Rw,
                             ushort_t* __restrict__ ys) {
    const int h = blockIdx.x;
    const int tid = threadIdx.x;
    const int lane = tid & 63;
    const int w = tid >> 6;

    __shared__ ushort_t h_lds[2 * 4 * 208];   // two buffers, [b][e] stride 208

    // R fragments: B[k=(lane>>4)*8+j][e = w*16 + (lane&15)]
    s8v Bf[4][6];
    {
        int col = w * 16 + (lane & 15);
        int kq0 = (lane >> 4) * 8;
#pragma unroll
        for (int g = 0; g < 4; ++g)
#pragma unroll
            for (int kt = 0; kt < 6; ++kt) {
                const float* rp = Rw + ((size_t)((g * NH_ + h) * DH_ + kt * 32 + kq0)) * DH_ + col;
                s8v f;
#pragma unroll
                for (int j = 0; j < 8; ++j) f[j] = (short)f2bf(rp[(size_t)j * DH_]);
                Bf[g][kt] = f;
            }
    }

    for (int i = tid; i < 2 * 4 * 208; i += 768) h_lds[i] = 0;

    const int b_id = lane >> 4;                 // batch this lane gates
    const int e_id = w * 16 + (lane & 15);      // e-column this lane gates
    const int a_off = ((lane & 15) >> 2) * 208 + (lane >> 4) * 8;  // A-frag elem offset in buffer
    const int hw_off = b_id * 208 + e_id;       // h-write elem offset in buffer

    float m_st = 0.f, c_st = 0.f, n_st = 0.f;
    const float LOG2E = 1.44269504088896f;

    // G pointer for this lane's (b,e); prefetch s=0
    const int gstride = NH_ * B_ * DH_ * 4;     // 12288 ushorts per s
    const ushort_t* gp = G + (((size_t)h * B_ + b_id) * DH_ + e_id) * 4;
    ushort4 gv_n = *(const ushort4*)gp;

    ushort_t* yp = ys + ((size_t)h * B_ + b_id) * DH_ + e_id;   // s-stride 3072

    __syncthreads();

    for (int s = 0; s < S_; ++s) {
        ushort4 gv = gv_n;
        if (s + 1 < S_) gp += gstride;          // uniform scalar branch
        gv_n = *(const ushort4*)gp;             // prefetch next step

        const int p = s & 1;
        const ushort_t* abuf = h_lds + p * 832 + a_off;

        s8v A[6];
#pragma unroll
        for (int kt = 0; kt < 6; ++kt)
            A[kt] = *(const s8v*)(abuf + kt * 32);

        f4v acc[4];
#pragma unroll
        for (int g = 0; g < 4; ++g) { acc[g][0] = 0.f; acc[g][1] = 0.f; acc[g][2] = 0.f; acc[g][3] = 0.f; }
#pragma unroll
        for (int kt = 0; kt < 6; ++kt)
#pragma unroll
            for (int g = 0; g < 4; ++g)
                acc[g] = mfma16(A[kt], Bf[g][kt], acc[g]);

        // gating — this lane's (b,e) pre-acts are acc[g][0]
        float it = acc[0][0] + bf2f(gv.x);
        float ft = acc[1][0] + bf2f(gv.y);
        float zt = acc[2][0] + bf2f(gv.z);
        float ot = acc[3][0] + bf2f(gv.w);

        float fm = ft + m_st;
        float mn = fmaxf(fm, it);
        float ia = __builtin_amdgcn_exp2f((it - mn) * LOG2E);
        float fa = __builtin_amdgcn_exp2f((fm - mn) * LOG2E);
        float ez = __builtin_amdgcn_exp2f(zt * (2.f * LOG2E));
        float th = 1.f - 2.f * __builtin_amdgcn_rcpf(ez + 1.f);
        float cn = fa * c_st + ia * th;
        float nn = fa * n_st + ia;
        float sg = __builtin_amdgcn_rcpf(1.f + __builtin_amdgcn_exp2f(-ot * LOG2E));
        float hn = sg * cn * __builtin_amdgcn_rcpf(nn);
        m_st = mn; c_st = cn; n_st = nn;

        ushort_t hb = f2bf(hn);
        h_lds[(1 - p) * 832 + hw_off] = hb;     // write next step's h buffer
        *yp = hb;
        yp += NH_ * B_ * DH_;
        __syncthreads();                        // h buffer ready for next step
    }
}

// ---------------------------------------------------------------------------
// Kernel 4: multi-head layernorm. One wave per (b,s,h) group of 192.
// ---------------------------------------------------------------------------
__global__ void ln_kernel(const ushort_t* __restrict__ ys, const float* __restrict__ gn,
                          float* __restrict__ out) {
    int gw = (blockIdx.x * blockDim.x + threadIdx.x) >> 6;   // 0 .. 32767
    int lane = threadIdx.x & 63;
    int b = gw & 3;
    int h = (gw >> 2) & 3;
    int s = gw >> 4;

    const ushort_t* yp = ys + (size_t)gw * DH_;
    float v0 = bf2f(yp[lane]);
    float v1 = bf2f(yp[lane + 64]);
    float v2 = bf2f(yp[lane + 128]);
    float sum = v0 + v1 + v2;
    float sq  = v0 * v0 + v1 * v1 + v2 * v2;
#pragma unroll
    for (int off = 32; off > 0; off >>= 1) {
        sum += __shfl_xor(sum, off, 64);
        sq  += __shfl_xor(sq,  off, 64);
    }
    float mu  = sum * (1.f / 192.f);
    float var = sq * (1.f / 192.f) - mu * mu;
    float rs  = rsqrtf(var + 1e-5f);

    float* op = out + (size_t)(b * S_ + s) * D_ + h * DH_;
    const float* gp = gn + h * DH_;
    op[lane]       = (v0 - mu) * rs * gp[lane];
    op[lane + 64]  = (v1 - mu) * rs * gp[lane + 64];
    op[lane + 128] = (v2 - mu) * rs * gp[lane + 128];
}

// ---------------------------------------------------------------------------
extern "C" void kernel_launch(void* const* d_in, const int* in_sizes, int n_in,
                              void* d_out, int out_size, void* d_ws, size_t ws_size,
                              hipStream_t stream) {
    const float* x     = (const float*)d_in[0];
    const float* ck    = (const float*)d_in[1];
    const float* cb    = (const float*)d_in[2];
    const float* Wi    = (const float*)d_in[3];
    const float* Wf    = (const float*)d_in[4];
    const float* Wz    = (const float*)d_in[5];
    const float* Wo    = (const float*)d_in[6];
    const float* Rw    = (const float*)d_in[7];
    const float* cbias = (const float*)d_in[8];
    const float* gn    = (const float*)d_in[9];
    float* out = (float*)d_out;

    const size_t nBSD = (size_t)B_ * S_ * D_;              // 6291456
    ushort_t* xconv = (ushort_t*)d_ws;
    ushort_t* xb    = xconv + nBSD;
    ushort_t* G     = xb + nBSD;                           // S*NH*B*DH*4 = 25165824
    ushort_t* ys    = G + (size_t)S_ * NH_ * 4 * B_ * DH_; // 6291456

    conv_kernel<<<dim3(B_ * S_ * D_ / 4 / 256), dim3(256), 0, stream>>>(x, ck, cb, xconv, xb);
    gates_kernel<<<dim3(32, NH_, 2), dim3(768), 0, stream>>>(xconv, xb, Wi, Wf, Wz, Wo, cbias, G);
    recur_kernel<<<dim3(NH_), dim3(768), 0, stream>>>(G, Rw, ys);
    ln_kernel<<<dim3(8192), dim3(256), 0, stream>>>(ys, gn, out);
}

// Round 3
// 2042.092 us; speedup vs baseline: 1.2392x; 1.0172x over previous
//
#include <hip/hip_runtime.h>

#define B_  4
#define S_  2048
#define D_  768
#define NH_ 4
#define DH_ 192

typedef short  s8v __attribute__((ext_vector_type(8)));
typedef float  f4v __attribute__((ext_vector_type(4)));
typedef unsigned short ushort_t;

static __device__ __forceinline__ ushort_t f2bf(float f) {
    union { float f; unsigned u; } v; v.f = f;
    unsigned r = v.u + 0x7fffu + ((v.u >> 16) & 1u);
    return (ushort_t)(r >> 16);
}
static __device__ __forceinline__ float bf2f(ushort_t b) {
    union { unsigned u; float f; } v; v.u = ((unsigned)b) << 16;
    return v.f;
}
static __device__ __forceinline__ f4v mfma16(s8v a, s8v b, f4v c) {
    return __builtin_amdgcn_mfma_f32_16x16x32_bf16(a, b, c, 0, 0, 0);
}

// ---------------------------------------------------------------------------
// Kernel 1: causal depthwise conv1d + swish -> x_conv (bf16); also x -> bf16.
// ---------------------------------------------------------------------------
__global__ void conv_kernel(const float* __restrict__ x, const float* __restrict__ ck,
                            const float* __restrict__ cb,
                            ushort_t* __restrict__ xconv, ushort_t* __restrict__ xb) {
    int idx = blockIdx.x * blockDim.x + threadIdx.x;   // over B*S*D/4
    const int nd4 = D_ / 4;
    int d4 = idx % nd4;
    int bs = idx / nd4;
    int s = bs % S_;
    int b = bs / S_;
    int d = d4 * 4;

    float4 acc = *(const float4*)(cb + d);
    float4 xcur = make_float4(0.f, 0.f, 0.f, 0.f);
#pragma unroll
    for (int k = 0; k < 4; ++k) {
        int sk = s - 3 + k;
        float4 xv = make_float4(0.f, 0.f, 0.f, 0.f);
        if (sk >= 0) xv = *(const float4*)(x + ((size_t)(b * S_ + sk) * D_ + d));
        if (k == 3) xcur = xv;
        float4 kv = *(const float4*)(ck + (size_t)k * D_ + d);
        acc.x += xv.x * kv.x; acc.y += xv.y * kv.y;
        acc.z += xv.z * kv.z; acc.w += xv.w * kv.w;
    }
    float c0 = acc.x / (1.f + __expf(-acc.x));
    float c1 = acc.y / (1.f + __expf(-acc.y));
    float c2 = acc.z / (1.f + __expf(-acc.z));
    float c3 = acc.w / (1.f + __expf(-acc.w));

    size_t base = (size_t)bs * D_ + d;
    ushort4 pc; pc.x = f2bf(c0); pc.y = f2bf(c1); pc.z = f2bf(c2); pc.w = f2bf(c3);
    *(ushort4*)(xconv + base) = pc;
    ushort4 px; px.x = f2bf(xcur.x); px.y = f2bf(xcur.y); px.z = f2bf(xcur.z); px.w = f2bf(xcur.w);
    *(ushort4*)(xb + base) = px;
}

// ---------------------------------------------------------------------------
// Kernel 2: gate pre-activation GEMMs.
// G layout: [s][h][b][e][g] bf16 (g in {i,f,z,o}), cell_bias folded in.
// grid: (32 s-blocks, NH, 2) ; p=0 -> {i,f} from x_conv ; p=1 -> {z,o} from x.
// ---------------------------------------------------------------------------
__launch_bounds__(768)
__global__ void gates_kernel(const ushort_t* __restrict__ xconv, const ushort_t* __restrict__ xb,
                             const float* __restrict__ Wi, const float* __restrict__ Wf,
                             const float* __restrict__ Wz, const float* __restrict__ Wo,
                             const float* __restrict__ cbias, ushort_t* __restrict__ G) {
    int sb = blockIdx.x, h = blockIdx.y, p = blockIdx.z;
    const ushort_t* X = (p == 0) ? xconv : xb;
    const float* W0 = (p == 0) ? Wi : Wz;
    const float* W1 = (p == 0) ? Wf : Wo;

    int tid = threadIdx.x;
    int lane = tid & 63;
    int w = tid >> 6;                 // 0..11 = e-tile

    int col = w * 16 + (lane & 15);   // e
    int kq0 = (lane >> 4) * 8;

    s8v B0[6], B1[6];
#pragma unroll
    for (int kt = 0; kt < 6; ++kt) {
        const float* w0p = W0 + ((size_t)(h * DH_ + kt * 32 + kq0)) * DH_ + col;
        const float* w1p = W1 + ((size_t)(h * DH_ + kt * 32 + kq0)) * DH_ + col;
        s8v f0, f1;
#pragma unroll
        for (int j = 0; j < 8; ++j) {
            f0[j] = (short)f2bf(w0p[(size_t)j * DH_]);
            f1[j] = (short)f2bf(w1p[(size_t)j * DH_]);
        }
        B0[kt] = f0; B1[kt] = f1;
    }
    float bias0 = cbias[(size_t)(2 * p) * D_ + h * DH_ + col];
    float bias1 = cbias[(size_t)(2 * p + 1) * D_ + h * DH_ + col];

    int b_l = lane & 3;
    int ds_l = (lane >> 2) & 3;

    for (int mt = 0; mt < 16; ++mt) {
        int s = sb * 64 + mt * 4 + ds_l;
        const ushort_t* ap = X + ((size_t)(b_l * S_ + s) * D_ + h * DH_ + kq0);
        s8v A[6];
#pragma unroll
        for (int kt = 0; kt < 6; ++kt) A[kt] = *(const s8v*)(ap + kt * 32);
        f4v a0 = {0.f, 0.f, 0.f, 0.f}, a1 = {0.f, 0.f, 0.f, 0.f};
#pragma unroll
        for (int kt = 0; kt < 6; ++kt) {
            a0 = mfma16(A[kt], B0[kt], a0);
            a1 = mfma16(A[kt], B1[kt], a1);
        }
        // epilogue: C row = (lane>>4)*4 + r ; r = batch, lane>>4 = s offset
        int sro = sb * 64 + mt * 4 + (lane >> 4);
#pragma unroll
        for (int r = 0; r < 4; ++r) {
            size_t idx = (((size_t)(sro * NH_ + h) * B_ + r) * DH_ + col) * 4;
            ushort2 pr;
            pr.x = f2bf(a0[r] + bias0);
            pr.y = f2bf(a1[r] + bias1);
            *(ushort2*)(G + idx + 2 * p) = pr;
        }
    }
}

// ---------------------------------------------------------------------------
// Kernel 3: sequential recurrence. One WG per head. 768 thr = 12 waves.
// Batch b occupies A-rows 4b..4b+3 (content h[row>>2]) so C-row 4b lands in
// lane 16b reg 0 -> every lane holds its own (b,e) pre-acts for all 4 gates.
// Raw lgkm-only barrier per step (the ys global store needs no ordering, so
// we skip the vmcnt(0) drain __syncthreads would impose); double-buffered h.
// ys layout: [s][h][b][e] bf16.
// ---------------------------------------------------------------------------
__launch_bounds__(768)
__global__ void recur_kernel(const ushort_t* __restrict__ G, const float* __restrict__ Rw,
                             ushort_t* __restrict__ ys) {
    const int h = blockIdx.x;
    const int tid = threadIdx.x;
    const int lane = tid & 63;
    const int w = tid >> 6;

    __shared__ ushort_t h_lds[2 * 4 * 208];   // two buffers, [b][e] stride 208

    // R fragments: B[k=(lane>>4)*8+j][e = w*16 + (lane&15)]
    s8v Bf[4][6];
    {
        int col = w * 16 + (lane & 15);
        int kq0 = (lane >> 4) * 8;
#pragma unroll
        for (int g = 0; g < 4; ++g)
#pragma unroll
            for (int kt = 0; kt < 6; ++kt) {
                const float* rp = Rw + ((size_t)((g * NH_ + h) * DH_ + kt * 32 + kq0)) * DH_ + col;
                s8v f;
#pragma unroll
                for (int j = 0; j < 8; ++j) f[j] = (short)f2bf(rp[(size_t)j * DH_]);
                Bf[g][kt] = f;
            }
    }

    for (int i = tid; i < 2 * 4 * 208; i += 768) h_lds[i] = 0;

    const int b_id = lane >> 4;                 // batch this lane gates
    const int e_id = w * 16 + (lane & 15);      // e-column this lane gates
    const int a_off = ((lane & 15) >> 2) * 208 + (lane >> 4) * 8;  // A-frag elem offset
    const int hw_off = b_id * 208 + e_id;       // h-write elem offset in buffer

    float m_st = 0.f, c_st = 0.f, n_st = 0.f;
    const float LOG2E = 1.44269504088896f;

    const int gstride = NH_ * B_ * DH_ * 4;     // 12288 ushorts per s
    const ushort_t* gp = G + (((size_t)h * B_ + b_id) * DH_ + e_id) * 4;
    ushort4 gv_n = *(const ushort4*)gp;

    ushort_t* yp = ys + ((size_t)h * B_ + b_id) * DH_ + e_id;   // s-stride 3072

    __syncthreads();

    for (int s = 0; s < S_; ++s) {
        ushort4 gv = gv_n;
        if (s + 1 < S_) gp += gstride;          // uniform scalar branch
        gv_n = *(const ushort4*)gp;             // prefetch next step

        const int p = s & 1;
        const ushort_t* abuf = h_lds + p * 832 + a_off;

        s8v A[6];
#pragma unroll
        for (int kt = 0; kt < 6; ++kt)
            A[kt] = *(const s8v*)(abuf + kt * 32);

        f4v acc[4];
#pragma unroll
        for (int g = 0; g < 4; ++g) { acc[g][0] = 0.f; acc[g][1] = 0.f; acc[g][2] = 0.f; acc[g][3] = 0.f; }
        // f and i gates first: they head the gating dependency chain
#pragma unroll
        for (int kt = 0; kt < 6; ++kt) acc[1] = mfma16(A[kt], Bf[1][kt], acc[1]);
#pragma unroll
        for (int kt = 0; kt < 6; ++kt) acc[0] = mfma16(A[kt], Bf[0][kt], acc[0]);
#pragma unroll
        for (int kt = 0; kt < 6; ++kt) acc[2] = mfma16(A[kt], Bf[2][kt], acc[2]);
#pragma unroll
        for (int kt = 0; kt < 6; ++kt) acc[3] = mfma16(A[kt], Bf[3][kt], acc[3]);

        // gating — this lane's (b,e) pre-acts are acc[g][0]
        float it = acc[0][0] + bf2f(gv.x);
        float ft = acc[1][0] + bf2f(gv.y);
        float zt = acc[2][0] + bf2f(gv.z);
        float ot = acc[3][0] + bf2f(gv.w);

        float fm = ft + m_st;
        float mn = fmaxf(fm, it);
        float ia = __builtin_amdgcn_exp2f((it - mn) * LOG2E);
        float fa = __builtin_amdgcn_exp2f((fm - mn) * LOG2E);
        float ez = __builtin_amdgcn_exp2f(zt * (2.f * LOG2E));
        float th = 1.f - 2.f * __builtin_amdgcn_rcpf(ez + 1.f);
        float cn = fa * c_st + ia * th;
        float nn = fa * n_st + ia;
        float sg = __builtin_amdgcn_rcpf(1.f + __builtin_amdgcn_exp2f(-ot * LOG2E));
        float hn = sg * cn * __builtin_amdgcn_rcpf(nn);
        m_st = mn; c_st = cn; n_st = nn;

        ushort_t hb = f2bf(hn);
        h_lds[(1 - p) * 832 + hw_off] = hb;     // write next step's h buffer

        // lgkm-only barrier: orders the LDS ping-pong without draining the
        // global store queue (ys stores have no in-kernel reader).
        asm volatile("s_waitcnt lgkmcnt(0)\n\ts_barrier" ::: "memory");

        *yp = hb;                                // off the critical path now
        yp += NH_ * B_ * DH_;
    }
}

// ---------------------------------------------------------------------------
// Kernel 4: multi-head layernorm. One wave per (b,s,h) group of 192.
// ---------------------------------------------------------------------------
__global__ void ln_kernel(const ushort_t* __restrict__ ys, const float* __restrict__ gn,
                          float* __restrict__ out) {
    int gw = (blockIdx.x * blockDim.x + threadIdx.x) >> 6;   // 0 .. 32767
    int lane = threadIdx.x & 63;
    int b = gw & 3;
    int h = (gw >> 2) & 3;
    int s = gw >> 4;

    const ushort_t* yp = ys + (size_t)gw * DH_;
    float v0 = bf2f(yp[lane]);
    float v1 = bf2f(yp[lane + 64]);
    float v2 = bf2f(yp[lane + 128]);
    float sum = v0 + v1 + v2;
    float sq  = v0 * v0 + v1 * v1 + v2 * v2;
#pragma unroll
    for (int off = 32; off > 0; off >>= 1) {
        sum += __shfl_xor(sum, off, 64);
        sq  += __shfl_xor(sq,  off, 64);
    }
    float mu  = sum * (1.f / 192.f);
    float var = sq * (1.f / 192.f) - mu * mu;
    float rs  = rsqrtf(var + 1e-5f);

    float* op = out + (size_t)(b * S_ + s) * D_ + h * DH_;
    const float* gp = gn + h * DH_;
    op[lane]       = (v0 - mu) * rs * gp[lane];
    op[lane + 64]  = (v1 - mu) * rs * gp[lane + 64];
    op[lane + 128] = (v2 - mu) * rs * gp[lane + 128];
}

// ---------------------------------------------------------------------------
extern "C" void kernel_launch(void* const* d_in, const int* in_sizes, int n_in,
                              void* d_out, int out_size, void* d_ws, size_t ws_size,
                              hipStream_t stream) {
    const float* x     = (const float*)d_in[0];
    const float* ck    = (const float*)d_in[1];
    const float* cb    = (const float*)d_in[2];
    const float* Wi    = (const float*)d_in[3];
    const float* Wf    = (const float*)d_in[4];
    const float* Wz    = (const float*)d_in[5];
    const float* Wo    = (const float*)d_in[6];
    const float* Rw    = (const float*)d_in[7];
    const float* cbias = (const float*)d_in[8];
    const float* gn    = (const float*)d_in[9];
    float* out = (float*)d_out;

    const size_t nBSD = (size_t)B_ * S_ * D_;              // 6291456
    ushort_t* xconv = (ushort_t*)d_ws;
    ushort_t* xb    = xconv + nBSD;
    ushort_t* G     = xb + nBSD;                           // S*NH*B*DH*4 = 25165824
    ushort_t* ys    = G + (size_t)S_ * NH_ * 4 * B_ * DH_; // 6291456

    conv_kernel<<<dim3(B_ * S_ * D_ / 4 / 256), dim3(256), 0, stream>>>(x, ck, cb, xconv, xb);
    gates_kernel<<<dim3(32, NH_, 2), dim3(768), 0, stream>>>(xconv, xb, Wi, Wf, Wz, Wo, cbias, G);
    recur_kernel<<<dim3(NH_), dim3(768), 0, stream>>>(G, Rw, ys);
    ln_kernel<<<dim3(8192), dim3(256), 0, stream>>>(ys, gn, out);
}